// Round 12
// baseline (177.485 us; speedup 1.0000x reference)
//
#include <hip/hip_runtime.h>

#define Fdim 128
#define Hdim 128
#define Odim 64
#define RT 128           // rows per block tile (128 -> 2 barriers/128 rows, all-wave GEMM2)
#define ECAP 64          // edge bucket capacity per output row (mean 12, Poisson tail ~1e-30)
#define NMLP 448         // mlp-role blocks
#define NSCAT 64         // scatter-role blocks (total 512 = 2 blocks/CU residency)
#define EPSV 1e-12f
#define ALPHAV 0.5f

typedef _Float16 h8_t __attribute__((ext_vector_type(8)));
typedef _Float16 h4_t __attribute__((ext_vector_type(4)));
typedef float f32x4 __attribute__((ext_vector_type(4)));

// LDS: W2T 16K + X 32K + H 32K = 80KB -> 2 blocks/CU (160KB)
#define W2T_OFF 0        // 64x128 f16, row=o-col, K-contig, swizzled (pre-built image)
#define X_OFF   16384    // 128x128 f16 x-tile
#define H_OFF   49152    // 128x128 f16 h-tile
#define LDS_BYTES 81920
#define WIMG_BYTES 49152 // wimg: W1T image [0,32768), W2T image [32768,49152)

// Fused: blocks [0,NMLP) = mlp (RT=128, all-wave GEMM2);
// blocks [NMLP, NMLP+NSCAT) = bucket scatter with inline nmt. Co-resident -> overlap.
// launch_bounds(512,2): VGPR cap 256; occupancy is LDS-capped at 2 blocks/CU anyway.
extern "C" __global__ __launch_bounds__(512, 2)
void fused_mlp_scatter(const float* __restrict__ X, const float* __restrict__ S,
                       const char* __restrict__ wimg, const float* __restrict__ b1,
                       const float* __restrict__ b2,
                       _Float16* __restrict__ Yh, float* __restrict__ out,
                       int TN, int rows_total, int ngroups,
                       const int* __restrict__ s_idxs, const int* __restrict__ t_idxs,
                       const float* __restrict__ wss, const int* __restrict__ fmap,
                       const float* __restrict__ mw, const float* __restrict__ tw,
                       int* __restrict__ cnt, int2* __restrict__ edat,
                       int Nn, int Tt, int Mm, int Eslab)
{
    const int tid = threadIdx.x;

    // ---------------- scatter role: last NSCAT blocks ----------------
    if (blockIdx.x >= NMLP) {
        if (edat == nullptr) return;   // fallback mode handles scatter elsewhere
        const int sb = blockIdx.x - NMLP;
        float mmax = -1e30f, tmax = -1e30f, msum = 0.f, tsum = 0.f;
        for (int i = 0; i < Mm; ++i) mmax = fmaxf(mmax, mw[i]);
        for (int i = 0; i < Mm; ++i) msum += expf(mw[i] - mmax);
        for (int i = 0; i < Tt; ++i) tmax = fmaxf(tmax, tw[i]);
        for (int i = 0; i < Tt; ++i) tsum += expf(tw[i] - tmax);
        const float inv = (1.0f - ALPHAV) / (msum * tsum);

        const int MT = Mm * Tt;
        for (int slab = 0; slab < MT; ++slab) {
            const int t  = slab % Tt;
            const int tN = t * Nn;
            const float scale = expf(mw[slab / Tt] - mmax) * expf(tw[t] - tmax) * inv;
            for (int i = sb * 512 + tid; i < Eslab; i += NSCAT * 512) {
                int e    = slab * Eslab + i;
                int si   = s_idxs[e];
                int yrow = tN + fmap[tN + t_idxs[e]];
                float w  = wss[e] * scale;
                int pos  = atomicAdd(cnt + si, 1);
                if (pos < ECAP)
                    edat[(size_t)si * ECAP + pos] = make_int2(yrow, __float_as_int(w));
            }
        }
        return;
    }

    // ---------------- mlp role ----------------
    extern __shared__ char smem[];
    const int wave = tid >> 6;   // 0..7
    const int lane = tid & 63;
    const int c = lane & 15;     // MFMA col/lane-low
    const int g = lane >> 4;     // MFMA lane-group

    // stage W2T image to LDS: pure linear copy, conflict-free
    #pragma unroll
    for (int i = 0; i < 2; ++i) {
        int idx = tid + i * 512;
        float4 v = *(const float4*)(wimg + 32768 + idx * 16);
        *(float4*)(smem + W2T_OFF + idx * 16) = v;
    }

    // W1 A-fragments in registers for all groups (wave owns h-cols [16w,16w+16))
    h8_t w1f[4];
    {
        int r0 = wave * 16 + c;
        #pragma unroll
        for (int kt = 0; kt < 4; ++kt)
            w1f[kt] = *(const h8_t*)(wimg + (((r0 << 8) + (kt << 6) + (g << 4)) ^ ((c & 7) << 4)));
    }

    // hoisted biases
    const int hbase = wave * 16 + 4 * g;
    float b1v[4];
    #pragma unroll
    for (int j = 0; j < 4; ++j) b1v[j] = b1[hbase + j];
    float bb[4];
    #pragma unroll
    for (int ct = 0; ct < 4; ++ct) bb[ct] = b2[ct * 16 + c];

    // prologue: load + stage first group's X (128 rows x 128 f32 -> f16, swizzled)
    float4 pf[8];
    int grp = blockIdx.x;
    #pragma unroll
    for (int it = 0; it < 8; ++it) {
        int idx = tid + it * 512;   // 0..4095
        int r = idx >> 5, c4 = idx & 31;
        int rowg = grp * RT + r;
        float4 v = make_float4(0.f, 0.f, 0.f, 0.f);
        if (rowg < TN)               v = *(const float4*)(X + (size_t)rowg * Fdim + c4 * 4);
        else if (rowg < rows_total)  v = *(const float4*)(S + (size_t)(rowg - TN) * Fdim + c4 * 4);
        pf[it] = v;
    }
    #pragma unroll
    for (int it = 0; it < 8; ++it) {
        int idx = tid + it * 512;
        int r = idx >> 5, c4 = idx & 31;
        h4_t hv;
        hv[0] = (_Float16)pf[it].x; hv[1] = (_Float16)pf[it].y;
        hv[2] = (_Float16)pf[it].z; hv[3] = (_Float16)pf[it].w;
        *(h4_t*)(smem + X_OFF + ((r * 256 + c4 * 8) ^ ((r & 7) << 4))) = hv;
    }
    __syncthreads();

    for (; grp < ngroups; grp += NMLP) {
        const int gnext = grp + NMLP;

        // issue prefetch loads for next group (latency hides under GEMM1+GEMM2)
        #pragma unroll
        for (int it = 0; it < 8; ++it) {
            int idx = tid + it * 512;
            int r = idx >> 5, c4 = idx & 31;
            int rowg = gnext * RT + r;
            float4 v = make_float4(0.f, 0.f, 0.f, 0.f);
            if (rowg < TN)               v = *(const float4*)(X + (size_t)rowg * Fdim + c4 * 4);
            else if (rowg < rows_total)  v = *(const float4*)(S + (size_t)(rowg - TN) * Fdim + c4 * 4);
            pf[it] = v;
        }

        // GEMM1': HT = (W1^T)@(X^T); wave w owns h-cols [16w,16w+16) x 128 rows; A from regs
        f32x4 acc[8];
        #pragma unroll
        for (int r = 0; r < 8; ++r) acc[r] = (f32x4){0.f, 0.f, 0.f, 0.f};

        #pragma unroll
        for (int kt = 0; kt < 4; ++kt) {
            #pragma unroll
            for (int rt = 0; rt < 8; ++rt) {
                int xr = rt * 16 + c;
                h8_t bf = *(const h8_t*)(smem + X_OFF + ((xr * 256 + kt * 64 + g * 16) ^ ((c & 7) << 4)));
                acc[rt] = __builtin_amdgcn_mfma_f32_16x16x32_f16(w1f[kt], bf, acc[rt], 0, 0, 0);
            }
        }

        // h = relu(acc + b1) -> H-buf
        #pragma unroll
        for (int rt = 0; rt < 8; ++rt) {
            int xr = rt * 16 + c;
            h4_t hv;
            #pragma unroll
            for (int j = 0; j < 4; ++j) {
                float hval = acc[rt][j] + b1v[j];
                hval = fmaxf(hval, 0.f);
                hv[j] = (_Float16)hval;
            }
            *(h4_t*)(smem + H_OFF + ((xr * 256 + hbase * 2) ^ ((xr & 7) << 4))) = hv;
        }
        __syncthreads();   // bar_a: H ready; all X reads done

        // GEMM2 + epilogue on ALL 8 waves: wave owns x-rows [16w,16w+16)
        {
            f32x4 acc2[4];
            #pragma unroll
            for (int ct = 0; ct < 4; ++ct) acc2[ct] = (f32x4){0.f, 0.f, 0.f, 0.f};

            #pragma unroll
            for (int kt = 0; kt < 4; ++kt) {
                int xr = wave * 16 + c;
                h8_t a = *(const h8_t*)(smem + H_OFF + ((xr * 256 + kt * 64 + g * 16) ^ ((xr & 7) << 4)));
                #pragma unroll
                for (int ct = 0; ct < 4; ++ct) {
                    int wr = ct * 16 + c;
                    h8_t bf = *(const h8_t*)(smem + W2T_OFF + ((wr * 256 + kt * 64 + g * 16) ^ ((c & 7) << 4)));
                    acc2[ct] = __builtin_amdgcn_mfma_f32_16x16x32_f16(a, bf, acc2[ct], 0, 0, 0);
                }
            }

            float y[4][4];
            float ssq[4] = {0.f, 0.f, 0.f, 0.f};
            #pragma unroll
            for (int ct = 0; ct < 4; ++ct) {
                #pragma unroll
                for (int j = 0; j < 4; ++j) {
                    float v = acc2[ct][j] + bb[ct];
                    y[ct][j] = v;
                    ssq[j] += v * v;
                }
            }
            #pragma unroll
            for (int j = 0; j < 4; ++j) {
                float s = ssq[j];
                s += __shfl_xor(s, 1);
                s += __shfl_xor(s, 2);
                s += __shfl_xor(s, 4);
                s += __shfl_xor(s, 8);
                float n  = fmaxf(sqrtf(s), EPSV);
                float sc = 10.0f / n;
                int rowg = grp * RT + wave * 16 + 4 * g + j;
                if (rowg < TN) {
                    _Float16* dst = Yh + (size_t)rowg * Odim;
                    #pragma unroll
                    for (int ct = 0; ct < 4; ++ct)
                        dst[ct * 16 + c] = (_Float16)(y[ct][j] * sc);
                } else if (rowg < rows_total) {
                    float* dst = out + (size_t)(rowg - TN) * Odim;
                    #pragma unroll
                    for (int ct = 0; ct < 4; ++ct)
                        dst[ct * 16 + c] = ALPHAV * y[ct][j] * sc;
                }
            }
        }

        // stage next X tile from prefetched regs (X-buf free since bar_a)
        #pragma unroll
        for (int it = 0; it < 8; ++it) {
            int idx = tid + it * 512;
            int r = idx >> 5, c4 = idx & 31;
            h4_t hv;
            hv[0] = (_Float16)pf[it].x; hv[1] = (_Float16)pf[it].y;
            hv[2] = (_Float16)pf[it].z; hv[3] = (_Float16)pf[it].w;
            *(h4_t*)(smem + X_OFF + ((r * 256 + c4 * 8) ^ ((r & 7) << 4))) = hv;
        }
        __syncthreads();   // bar_b: next X ready; H reads done
    }
}

// prep: blocks [0,96) build pre-swizzled f16 weight images; rest zero cnt
extern "C" __global__ __launch_bounds__(256)
void prep_all(const float* __restrict__ W1, const float* __restrict__ W2,
              char* __restrict__ wimg, int* __restrict__ cnt, int B)
{
    if (blockIdx.x < 96) {
        int idx = blockIdx.x * 256 + threadIdx.x;
        if (idx < 16384) {
            int h = idx >> 7, f = idx & 127;
            float v = W1[(size_t)f * Hdim + h];
            int byte = (h * 256 + f * 2) ^ ((h & 7) << 4);
            *(_Float16*)(wimg + byte) = (_Float16)v;
        } else if (idx < 24576) {
            int i2 = idx - 16384;
            int o = i2 >> 7, k = i2 & 127;
            float v = W2[(size_t)k * Odim + o];
            int byte = 32768 + ((o * 256 + k * 2) ^ ((o & 7) << 4));
            *(_Float16*)(wimg + byte) = (_Float16)v;
        }
    } else {
        int i = (blockIdx.x - 96) * 256 + threadIdx.x;
        if (i < B) cnt[i] = 0;
    }
}

// one wave per row; 8 edge-groups x 8 channel-lanes; 16B h8 loads; fused blend+log_softmax
extern "C" __global__ __launch_bounds__(256)
void row_gather(const int2* __restrict__ edgedat, const int* __restrict__ cnt,
                const _Float16* __restrict__ Yh, float* __restrict__ out, int B)
{
    const int lane = threadIdx.x & 63;
    const int grp8 = lane >> 3;     // edge subgroup 0..7
    const int sub  = lane & 7;      // channel slice 0..7
    int b = blockIdx.x * 4 + (threadIdx.x >> 6);
    if (b >= B) return;
    int n = cnt[b];
    if (n > ECAP) n = ECAP;
    const int2* ebase = edgedat + (size_t)b * ECAP;

    float acc[8];
    #pragma unroll
    for (int j = 0; j < 8; ++j) acc[j] = 0.f;

    for (int e = grp8; e < n; e += 8) {
        int2 ed = ebase[e];
        float w = __int_as_float(ed.y);
        h8_t y8 = *(const h8_t*)(Yh + (size_t)ed.x * Odim + sub * 8);
        #pragma unroll
        for (int j = 0; j < 8; ++j) acc[j] += w * (float)y8[j];
    }
    #pragma unroll
    for (int d = 8; d < 64; d <<= 1) {
        #pragma unroll
        for (int j = 0; j < 8; ++j) acc[j] += __shfl_xor(acc[j], d);
    }
    const float* orow = out + (size_t)b * Odim + sub * 8;
    float v[8];
    #pragma unroll
    for (int j = 0; j < 8; ++j) v[j] = orow[j] + acc[j];

    float mx = v[0];
    #pragma unroll
    for (int j = 1; j < 8; ++j) mx = fmaxf(mx, v[j]);
    #pragma unroll
    for (int d = 1; d < 8; d <<= 1) mx = fmaxf(mx, __shfl_xor(mx, d));
    float sm = 0.f;
    #pragma unroll
    for (int j = 0; j < 8; ++j) sm += expf(v[j] - mx);
    #pragma unroll
    for (int d = 1; d < 8; d <<= 1) sm += __shfl_xor(sm, d);
    float lg = mx + logf(sm);

    if (grp8 == 0) {
        float* dst = out + (size_t)b * Odim + sub * 8;
        #pragma unroll
        for (int j = 0; j < 8; ++j) dst[j] = v[j] - lg;
    }
}

// ---------------- fallback path (ws too small): float atomics ----------------

extern "C" __global__ __launch_bounds__(256)
void edge_scatter(const int* __restrict__ s_idxs, const int* __restrict__ t_idxs,
                  const float* __restrict__ weightss, const int* __restrict__ fmap,
                  const _Float16* __restrict__ Yh, const float* __restrict__ mw,
                  const float* __restrict__ tw,
                  float* __restrict__ out, int Nn, int Tt, int Mm, int Eslab)
{
    const int lane = threadIdx.x & 63;
    const int slab = blockIdx.y;
    const int t    = slab % Tt;
    const int tN   = t * Nn;
    float mmax = -1e30f, tmax = -1e30f, msum = 0.f, tsum = 0.f;
    for (int i = 0; i < Mm; ++i) mmax = fmaxf(mmax, mw[i]);
    for (int i = 0; i < Mm; ++i) msum += expf(mw[i] - mmax);
    for (int i = 0; i < Tt; ++i) tmax = fmaxf(tmax, tw[i]);
    for (int i = 0; i < Tt; ++i) tsum += expf(tw[i] - tmax);
    const float scale = (1.0f - ALPHAV) * expf(mw[slab / Tt] - mmax) * expf(tw[t] - tmax)
                        / (msum * tsum);

    const int wid  = blockIdx.x * (blockDim.x >> 6) + (threadIdx.x >> 6);
    const int off  = wid * 64;
    if (off >= Eslab) return;

    const int ebase = slab * Eslab + off;
    int   e_ok = (off + lane) < Eslab;
    int   eidx = ebase + (e_ok ? lane : 0);
    int   si   = s_idxs[eidx];
    int   ti   = t_idxs[eidx];
    float w    = e_ok ? (weightss[eidx] * scale) : 0.0f;
    int   yrow = tN + fmap[tN + ti];

    #pragma unroll 8
    for (int i = 0; i < 64; ++i) {
        int   nd = __builtin_amdgcn_readlane(yrow, i);
        int   s  = __builtin_amdgcn_readlane(si, i);
        float ws = __uint_as_float(__builtin_amdgcn_readlane(__float_as_uint(w), i));
        float yv = (float)Yh[(size_t)nd * Odim + lane];
        atomicAdd(out + (size_t)s * Odim + lane, yv * ws);
    }
}

extern "C" __global__ __launch_bounds__(256)
void log_softmax_rows(float* __restrict__ out, int Brows)
{
    int lane = threadIdx.x & 63;
    int r = blockIdx.x * 4 + (threadIdx.x >> 6);
    if (r >= Brows) return;
    float* row = out + (size_t)r * Odim;
    float v = row[lane];
    float mx = v;
    for (int off = 32; off > 0; off >>= 1) mx = fmaxf(mx, __shfl_xor(mx, off));
    float ex = expf(v - mx);
    float s = ex;
    for (int off = 32; off > 0; off >>= 1) s += __shfl_xor(s, off);
    row[lane] = v - mx - logf(s);
}

extern "C" void kernel_launch(void* const* d_in, const int* in_sizes, int n_in,
                              void* d_out, int out_size, void* d_ws, size_t ws_size,
                              hipStream_t stream)
{
    const float* X   = (const float*)d_in[0];
    const float* S   = (const float*)d_in[1];
    const int*   fmap= (const int*)d_in[2];
    const int*   sidx= (const int*)d_in[3];
    const int*   tidx= (const int*)d_in[4];
    const float* wss = (const float*)d_in[5];
    const float* W1  = (const float*)d_in[7];
    const float* b1  = (const float*)d_in[8];
    const float* W2  = (const float*)d_in[9];
    const float* b2  = (const float*)d_in[10];
    const float* mw  = (const float*)d_in[11];
    const float* tw  = (const float*)d_in[12];
    float* out = (float*)d_out;

    const int M = in_sizes[11];
    const int T = in_sizes[12];
    const int H = in_sizes[8];
    const int Fv = in_sizes[7] / H;      // 128
    const int N = in_sizes[2] / T;
    const int nedges = in_sizes[3];
    const int E = nedges / (M * T);
    const int B = in_sizes[1] / Fv;
    const int TN = T * N;
    const int rows_total = TN + B;
    const int ngroups = (rows_total + RT - 1) / RT;

    // ---- workspace carve-up ----
    char* wp = (char*)d_ws;
    size_t used = 0;
    auto alloc = [&](size_t bytes) -> char* {
        char* p = wp + used;
        used = (used + bytes + 255) & ~(size_t)255;
        return p;
    };
    _Float16* Yh   = (_Float16*)alloc((size_t)TN * Odim * sizeof(_Float16));
    char*     wimg = (char*)    alloc((size_t)WIMG_BYTES);
    int*      cntp = (int*)     alloc((size_t)B * sizeof(int));
    int2*     edat = (int2*)    alloc((size_t)B * ECAP * sizeof(int2));
    bool bucket_ok = used <= ws_size;

    hipFuncSetAttribute((const void*)fused_mlp_scatter,
                        hipFuncAttributeMaxDynamicSharedMemorySize, LDS_BYTES);

    const int zb = (B + 255) / 256;
    prep_all<<<96 + zb, 256, 0, stream>>>(W1, W2, wimg, cntp, B);

    if (bucket_ok) {
        fused_mlp_scatter<<<NMLP + NSCAT, 512, LDS_BYTES, stream>>>(
            X, S, wimg, b1, b2, Yh, out, TN, rows_total, ngroups,
            sidx, tidx, wss, fmap, mw, tw, cntp, edat, N, T, M, E);
        row_gather<<<(B + 3) / 4, 256, 0, stream>>>(edat, cntp, Yh, out, B);
    } else {
        fused_mlp_scatter<<<NMLP + NSCAT, 512, LDS_BYTES, stream>>>(
            X, S, wimg, b1, b2, Yh, out, TN, rows_total, ngroups,
            sidx, tidx, wss, fmap, mw, tw, cntp, nullptr, N, T, M, E);
        int waves_per_slab = (E + 63) / 64;
        dim3 sg((waves_per_slab + 3) / 4, M * T);
        edge_scatter<<<sg, 256, 0, stream>>>(sidx, tidx, wss, fmap, Yh, mw, tw, out,
                                             N, T, M, E);
        log_softmax_rows<<<(B + 3) / 4, 256, 0, stream>>>(out, B);
    }
}

// Round 13
// 146.074 us; speedup vs baseline: 1.2150x; 1.2150x over previous
//
#include <hip/hip_runtime.h>

#define Fdim 128
#define Hdim 128
#define Odim 64
#define RT 64            // rows per block tile
#define ECAP 64          // edge bucket capacity per output row (mean 12)
#define EPSV 1e-12f
#define ALPHAV 0.5f

typedef _Float16 h8_t __attribute__((ext_vector_type(8)));
typedef _Float16 h4_t __attribute__((ext_vector_type(4)));
typedef float f32x4 __attribute__((ext_vector_type(4)));

// LDS: W2T 16K + X dbuf 32K + H dbuf 32K = 80KB -> 2 blocks/CU
#define W2T_OFF 0
#define X0_OFF  16384    // X[cur] = X0_OFF + cur*16384
#define H0_OFF  49152    // H[cur] = H0_OFF + cur*16384
#define LDS_BYTES 81920
#define WIMG_BYTES 49152 // wimg: W1T image [0,32768), W2T image [32768,49152)

// 512 thr / 8 waves; double-buffered X,H -> ONE barrier per 64-row group.
extern "C" __global__ __launch_bounds__(512, 4)
void mlp_all(const float* __restrict__ X, const float* __restrict__ S,
             const char* __restrict__ wimg, const float* __restrict__ b1,
             const float* __restrict__ b2,
             _Float16* __restrict__ Yh, float* __restrict__ out,
             int TN, int rows_total, int ngroups)
{
    extern __shared__ char smem[];
    const int tid  = threadIdx.x;
    const int wave = tid >> 6;   // 0..7
    const int lane = tid & 63;
    const int c = lane & 15;     // MFMA col/lane-low
    const int g = lane >> 4;     // MFMA lane-group

    // stage W2T image to LDS: linear copy, conflict-free
    #pragma unroll
    for (int i = 0; i < 2; ++i) {
        int idx = tid + i * 512;
        float4 v = *(const float4*)(wimg + 32768 + idx * 16);
        *(float4*)(smem + W2T_OFF + idx * 16) = v;
    }

    // W1 A-fragments in registers (wave owns h-cols [16w,16w+16))
    h8_t w1f[4];
    {
        int r0 = wave * 16 + c;
        #pragma unroll
        for (int kt = 0; kt < 4; ++kt)
            w1f[kt] = *(const h8_t*)(wimg + (((r0 << 8) + (kt << 6) + (g << 4)) ^ ((c & 7) << 4)));
    }

    // hoisted biases
    const int hbase = wave * 16 + 4 * g;
    float b1v[4];
    #pragma unroll
    for (int j = 0; j < 4; ++j) b1v[j] = b1[hbase + j];
    float bb[4];
    #pragma unroll
    for (int ct = 0; ct < 4; ++ct) bb[ct] = b2[ct * 16 + c];

    // prologue: load + stage first group's X into X0
    float4 pf[4];
    int grp = blockIdx.x;
    #pragma unroll
    for (int it = 0; it < 4; ++it) {
        int idx = tid + it * 512;
        int r = idx >> 5, c4 = idx & 31;
        int rowg = grp * RT + r;
        float4 v = make_float4(0.f, 0.f, 0.f, 0.f);
        if (rowg < TN)               v = *(const float4*)(X + (size_t)rowg * Fdim + c4 * 4);
        else if (rowg < rows_total)  v = *(const float4*)(S + (size_t)(rowg - TN) * Fdim + c4 * 4);
        pf[it] = v;
    }
    #pragma unroll
    for (int it = 0; it < 4; ++it) {
        int idx = tid + it * 512;
        int r = idx >> 5, c4 = idx & 31;
        h4_t hv;
        hv[0] = (_Float16)pf[it].x; hv[1] = (_Float16)pf[it].y;
        hv[2] = (_Float16)pf[it].z; hv[3] = (_Float16)pf[it].w;
        *(h4_t*)(smem + X0_OFF + ((r * 256 + c4 * 8) ^ ((r & 7) << 4))) = hv;
    }
    __syncthreads();

    int cur = 0;
    for (; grp < ngroups; grp += gridDim.x, cur ^= 1) {
        const int gnext = grp + gridDim.x;
        const int xb = X0_OFF + cur * 16384;
        const int hb = H0_OFF + cur * 16384;
        const int xn = X0_OFF + (cur ^ 1) * 16384;

        // issue prefetch loads for next group (hides under GEMM1)
        #pragma unroll
        for (int it = 0; it < 4; ++it) {
            int idx = tid + it * 512;
            int r = idx >> 5, c4 = idx & 31;
            int rowg = gnext * RT + r;
            float4 v = make_float4(0.f, 0.f, 0.f, 0.f);
            if (rowg < TN)               v = *(const float4*)(X + (size_t)rowg * Fdim + c4 * 4);
            else if (rowg < rows_total)  v = *(const float4*)(S + (size_t)(rowg - TN) * Fdim + c4 * 4);
            pf[it] = v;
        }

        // GEMM1': HT = (W1^T)@(X^T); A from regs, B from X[cur]
        f32x4 acc[4];
        #pragma unroll
        for (int r = 0; r < 4; ++r) acc[r] = (f32x4){0.f, 0.f, 0.f, 0.f};

        #pragma unroll
        for (int kt = 0; kt < 4; ++kt) {
            #pragma unroll
            for (int rt = 0; rt < 4; ++rt) {
                int xr = rt * 16 + c;
                h8_t bf = *(const h8_t*)(smem + xb + ((xr * 256 + kt * 64 + g * 16) ^ ((c & 7) << 4)));
                acc[rt] = __builtin_amdgcn_mfma_f32_16x16x32_f16(w1f[kt], bf, acc[rt], 0, 0, 0);
            }
        }

        // h = relu(acc + b1) -> H[cur]
        #pragma unroll
        for (int rt = 0; rt < 4; ++rt) {
            int xr = rt * 16 + c;
            h4_t hv;
            #pragma unroll
            for (int j = 0; j < 4; ++j) {
                float hval = acc[rt][j] + b1v[j];
                hval = fmaxf(hval, 0.f);
                hv[j] = (_Float16)hval;
            }
            *(h4_t*)(smem + hb + ((xr * 256 + hbase * 2) ^ ((xr & 7) << 4))) = hv;
        }

        // stage next X tile into X[cur^1] (prev GEMM1 on that buf finished 2 iters ago)
        #pragma unroll
        for (int it = 0; it < 4; ++it) {
            int idx = tid + it * 512;
            int r = idx >> 5, c4 = idx & 31;
            h4_t hv;
            hv[0] = (_Float16)pf[it].x; hv[1] = (_Float16)pf[it].y;
            hv[2] = (_Float16)pf[it].z; hv[3] = (_Float16)pf[it].w;
            *(h4_t*)(smem + xn + ((r * 256 + c4 * 8) ^ ((r & 7) << 4))) = hv;
        }

        __syncthreads();   // the ONE barrier: H[cur] ready + X[cur^1] ready

        // GEMM2 + epilogue on waves 0..3; waves 4..7 run ahead into next GEMM1
        if (wave < 4) {
            f32x4 acc2[4];
            #pragma unroll
            for (int ct = 0; ct < 4; ++ct) acc2[ct] = (f32x4){0.f, 0.f, 0.f, 0.f};

            #pragma unroll
            for (int kt = 0; kt < 4; ++kt) {
                int xr = wave * 16 + c;
                h8_t a = *(const h8_t*)(smem + hb + ((xr * 256 + kt * 64 + g * 16) ^ ((xr & 7) << 4)));
                #pragma unroll
                for (int ct = 0; ct < 4; ++ct) {
                    int wr = ct * 16 + c;
                    h8_t bf = *(const h8_t*)(smem + W2T_OFF + ((wr * 256 + kt * 64 + g * 16) ^ ((c & 7) << 4)));
                    acc2[ct] = __builtin_amdgcn_mfma_f32_16x16x32_f16(a, bf, acc2[ct], 0, 0, 0);
                }
            }

            float y[4][4];
            float ssq[4] = {0.f, 0.f, 0.f, 0.f};
            #pragma unroll
            for (int ct = 0; ct < 4; ++ct) {
                #pragma unroll
                for (int j = 0; j < 4; ++j) {
                    float v = acc2[ct][j] + bb[ct];
                    y[ct][j] = v;
                    ssq[j] += v * v;
                }
            }
            #pragma unroll
            for (int j = 0; j < 4; ++j) {
                float s = ssq[j];
                s += __shfl_xor(s, 1);
                s += __shfl_xor(s, 2);
                s += __shfl_xor(s, 4);
                s += __shfl_xor(s, 8);
                float n  = fmaxf(sqrtf(s), EPSV);
                float sc = 10.0f / n;
                int rowg = grp * RT + wave * 16 + 4 * g + j;
                if (rowg < TN) {
                    _Float16* dst = Yh + (size_t)rowg * Odim;
                    #pragma unroll
                    for (int ct = 0; ct < 4; ++ct)
                        dst[ct * 16 + c] = (_Float16)(y[ct][j] * sc);
                } else if (rowg < rows_total) {
                    float* dst = out + (size_t)(rowg - TN) * Odim;
                    #pragma unroll
                    for (int ct = 0; ct < 4; ++ct)
                        dst[ct * 16 + c] = ALPHAV * y[ct][j] * sc;
                }
            }
        }
        // no second barrier: next iter's H/X writes go to the other buffers
    }
}

// prep: blocks [0,96) build pre-swizzled f16 weight images; rest zero cnt
extern "C" __global__ __launch_bounds__(256)
void prep_all(const float* __restrict__ W1, const float* __restrict__ W2,
              char* __restrict__ wimg, int* __restrict__ cnt, int B)
{
    if (blockIdx.x < 96) {
        int idx = blockIdx.x * 256 + threadIdx.x;
        if (idx < 16384) {
            int h = idx >> 7, f = idx & 127;
            float v = W1[(size_t)f * Hdim + h];
            int byte = (h * 256 + f * 2) ^ ((h & 7) << 4);
            *(_Float16*)(wimg + byte) = (_Float16)v;
        } else if (idx < 24576) {
            int i2 = idx - 16384;
            int o = i2 >> 7, k = i2 & 127;
            float v = W2[(size_t)k * Odim + o];
            int byte = 32768 + ((o * 256 + k * 2) ^ ((o & 7) << 4));
            *(_Float16*)(wimg + byte) = (_Float16)v;
        }
    } else {
        int i = (blockIdx.x - 96) * 256 + threadIdx.x;
        if (i < B) cnt[i] = 0;
    }
}

// bucket scatter with inline nmt (separate kernel for clean attribution)
extern "C" __global__ __launch_bounds__(256)
void scatter_edges(const int* __restrict__ s_idxs, const int* __restrict__ t_idxs,
                   const float* __restrict__ wss, const int* __restrict__ fmap,
                   const float* __restrict__ mw, const float* __restrict__ tw,
                   int* __restrict__ cnt, int2* __restrict__ edat,
                   int Nn, int Tt, int Mm, int Eslab)
{
    const int slab = blockIdx.y;          // m*T + t
    const int t    = slab % Tt;
    const int tN   = t * Nn;
    float mmax = -1e30f, tmax = -1e30f, msum = 0.f, tsum = 0.f;
    for (int i = 0; i < Mm; ++i) mmax = fmaxf(mmax, mw[i]);
    for (int i = 0; i < Mm; ++i) msum += expf(mw[i] - mmax);
    for (int i = 0; i < Tt; ++i) tmax = fmaxf(tmax, tw[i]);
    for (int i = 0; i < Tt; ++i) tsum += expf(tw[i] - tmax);
    const float scale = (1.0f - ALPHAV) * expf(mw[slab / Tt] - mmax) * expf(tw[t] - tmax)
                        / (msum * tsum);

    int i = blockIdx.x * 256 + threadIdx.x;
    if (i >= Eslab) return;
    int e = slab * Eslab + i;
    int si   = s_idxs[e];
    int yrow = tN + fmap[tN + t_idxs[e]];
    float w  = wss[e] * scale;
    int pos = atomicAdd(cnt + si, 1);
    if (pos < ECAP)
        edat[(size_t)si * ECAP + pos] = make_int2(yrow, __float_as_int(w));
}

// one wave per row; 8 edge-groups x 8 channel-lanes; fused blend + log_softmax
extern "C" __global__ __launch_bounds__(256)
void row_gather(const int2* __restrict__ edgedat, const int* __restrict__ cnt,
                const _Float16* __restrict__ Yh, float* __restrict__ out, int B)
{
    const int lane = threadIdx.x & 63;
    const int grp8 = lane >> 3;
    const int sub  = lane & 7;
    int b = blockIdx.x * 4 + (threadIdx.x >> 6);
    if (b >= B) return;
    int n = cnt[b];
    if (n > ECAP) n = ECAP;
    const int2* ebase = edgedat + (size_t)b * ECAP;

    float acc[8];
    #pragma unroll
    for (int j = 0; j < 8; ++j) acc[j] = 0.f;

    for (int e = grp8; e < n; e += 8) {
        int2 ed = ebase[e];
        float w = __int_as_float(ed.y);
        h8_t y8 = *(const h8_t*)(Yh + (size_t)ed.x * Odim + sub * 8);
        #pragma unroll
        for (int j = 0; j < 8; ++j) acc[j] += w * (float)y8[j];
    }
    #pragma unroll
    for (int d = 8; d < 64; d <<= 1) {
        #pragma unroll
        for (int j = 0; j < 8; ++j) acc[j] += __shfl_xor(acc[j], d);
    }
    const float* orow = out + (size_t)b * Odim + sub * 8;
    float v[8];
    #pragma unroll
    for (int j = 0; j < 8; ++j) v[j] = orow[j] + acc[j];

    float mx = v[0];
    #pragma unroll
    for (int j = 1; j < 8; ++j) mx = fmaxf(mx, v[j]);
    #pragma unroll
    for (int d = 1; d < 8; d <<= 1) mx = fmaxf(mx, __shfl_xor(mx, d));
    float sm = 0.f;
    #pragma unroll
    for (int j = 0; j < 8; ++j) sm += expf(v[j] - mx);
    #pragma unroll
    for (int d = 1; d < 8; d <<= 1) sm += __shfl_xor(sm, d);
    float lg = mx + logf(sm);

    if (grp8 == 0) {
        float* dst = out + (size_t)b * Odim + sub * 8;
        #pragma unroll
        for (int j = 0; j < 8; ++j) dst[j] = v[j] - lg;
    }
}

// ---------------- fallback path (ws too small): float atomics ----------------

extern "C" __global__ __launch_bounds__(256)
void edge_scatter(const int* __restrict__ s_idxs, const int* __restrict__ t_idxs,
                  const float* __restrict__ weightss, const int* __restrict__ fmap,
                  const _Float16* __restrict__ Yh, const float* __restrict__ mw,
                  const float* __restrict__ tw,
                  float* __restrict__ out, int Nn, int Tt, int Mm, int Eslab)
{
    const int lane = threadIdx.x & 63;
    const int slab = blockIdx.y;
    const int t    = slab % Tt;
    const int tN   = t * Nn;
    float mmax = -1e30f, tmax = -1e30f, msum = 0.f, tsum = 0.f;
    for (int i = 0; i < Mm; ++i) mmax = fmaxf(mmax, mw[i]);
    for (int i = 0; i < Mm; ++i) msum += expf(mw[i] - mmax);
    for (int i = 0; i < Tt; ++i) tmax = fmaxf(tmax, tw[i]);
    for (int i = 0; i < Tt; ++i) tsum += expf(tw[i] - tmax);
    const float scale = (1.0f - ALPHAV) * expf(mw[slab / Tt] - mmax) * expf(tw[t] - tmax)
                        / (msum * tsum);

    const int wid  = blockIdx.x * (blockDim.x >> 6) + (threadIdx.x >> 6);
    const int off  = wid * 64;
    if (off >= Eslab) return;

    const int ebase = slab * Eslab + off;
    int   e_ok = (off + lane) < Eslab;
    int   eidx = ebase + (e_ok ? lane : 0);
    int   si   = s_idxs[eidx];
    int   ti   = t_idxs[eidx];
    float w    = e_ok ? (weightss[eidx] * scale) : 0.0f;
    int   yrow = tN + fmap[tN + ti];

    #pragma unroll 8
    for (int i = 0; i < 64; ++i) {
        int   nd = __builtin_amdgcn_readlane(yrow, i);
        int   s  = __builtin_amdgcn_readlane(si, i);
        float ws = __uint_as_float(__builtin_amdgcn_readlane(__float_as_uint(w), i));
        float yv = (float)Yh[(size_t)nd * Odim + lane];
        atomicAdd(out + (size_t)s * Odim + lane, yv * ws);
    }
}

extern "C" __global__ __launch_bounds__(256)
void log_softmax_rows(float* __restrict__ out, int Brows)
{
    int lane = threadIdx.x & 63;
    int r = blockIdx.x * 4 + (threadIdx.x >> 6);
    if (r >= Brows) return;
    float* row = out + (size_t)r * Odim;
    float v = row[lane];
    float mx = v;
    for (int off = 32; off > 0; off >>= 1) mx = fmaxf(mx, __shfl_xor(mx, off));
    float ex = expf(v - mx);
    float s = ex;
    for (int off = 32; off > 0; off >>= 1) s += __shfl_xor(s, off);
    row[lane] = v - mx - logf(s);
}

extern "C" void kernel_launch(void* const* d_in, const int* in_sizes, int n_in,
                              void* d_out, int out_size, void* d_ws, size_t ws_size,
                              hipStream_t stream)
{
    const float* X   = (const float*)d_in[0];
    const float* S   = (const float*)d_in[1];
    const int*   fmap= (const int*)d_in[2];
    const int*   sidx= (const int*)d_in[3];
    const int*   tidx= (const int*)d_in[4];
    const float* wss = (const float*)d_in[5];
    const float* W1  = (const float*)d_in[7];
    const float* b1  = (const float*)d_in[8];
    const float* W2  = (const float*)d_in[9];
    const float* b2  = (const float*)d_in[10];
    const float* mw  = (const float*)d_in[11];
    const float* tw  = (const float*)d_in[12];
    float* out = (float*)d_out;

    const int M = in_sizes[11];
    const int T = in_sizes[12];
    const int H = in_sizes[8];
    const int Fv = in_sizes[7] / H;      // 128
    const int N = in_sizes[2] / T;
    const int nedges = in_sizes[3];
    const int E = nedges / (M * T);
    const int B = in_sizes[1] / Fv;
    const int TN = T * N;
    const int rows_total = TN + B;
    const int ngroups = (rows_total + RT - 1) / RT;

    // ---- workspace carve-up ----
    char* wp = (char*)d_ws;
    size_t used = 0;
    auto alloc = [&](size_t bytes) -> char* {
        char* p = wp + used;
        used = (used + bytes + 255) & ~(size_t)255;
        return p;
    };
    _Float16* Yh   = (_Float16*)alloc((size_t)TN * Odim * sizeof(_Float16));
    char*     wimg = (char*)    alloc((size_t)WIMG_BYTES);
    int*      cntp = (int*)     alloc((size_t)B * sizeof(int));
    int2*     edat = (int2*)    alloc((size_t)B * ECAP * sizeof(int2));
    bool bucket_ok = used <= ws_size;

    hipFuncSetAttribute((const void*)mlp_all,
                        hipFuncAttributeMaxDynamicSharedMemorySize, LDS_BYTES);

    const int zb = (B + 255) / 256;
    prep_all<<<96 + zb, 256, 0, stream>>>(W1, W2, wimg, cntp, B);

    if (bucket_ok) {
        dim3 sg((E + 255) / 256, M * T);
        scatter_edges<<<sg, 256, 0, stream>>>(sidx, tidx, wss, fmap, mw, tw,
                                              cntp, edat, N, T, M, E);
        mlp_all<<<512, 512, LDS_BYTES, stream>>>(X, S, wimg, b1, b2, Yh, out,
                                                 TN, rows_total, ngroups);
        row_gather<<<(B + 3) / 4, 256, 0, stream>>>(edat, cntp, Yh, out, B);
    } else {
        mlp_all<<<512, 512, LDS_BYTES, stream>>>(X, S, wimg, b1, b2, Yh, out,
                                                 TN, rows_total, ngroups);
        int waves_per_slab = (E + 63) / 64;
        dim3 sg((waves_per_slab + 3) / 4, M * T);
        edge_scatter<<<sg, 256, 0, stream>>>(sidx, tidx, wss, fmap, Yh, mw, tw, out,
                                             N, T, M, E);
        log_softmax_rows<<<(B + 3) / 4, 256, 0, stream>>>(out, B);
    }
}